// Round 5
// baseline (195.423 us; speedup 1.0000x reference)
//
#include <hip/hip_runtime.h>
#include <hip/hip_bf16.h>
#include <math.h>

typedef short bf16x8 __attribute__((ext_vector_type(8)));
typedef float f32x4 __attribute__((ext_vector_type(4)));

#define B_HALF 2048
#define N_TOT  4096
#define D_DIM  128
#define K_DIM  512
#define BK     64
#define NGRP   32
#define NBLK   528   // triangular 32x32 tile grid

// ---------------------------------------------------------------------------
// Flag/counter state (module .bss -> zero at load). All padded to 128B lines.
// Protocol guarantees every counter is reset to 0 by the final winner before
// kernel end, so graph replays are deterministic. No grid-wide barrier, no
// contended spin: ready_f is read-only spun (set once); done_rg/final_done
// are increment-only (the winner proceeds, nobody waits on them).
// ---------------------------------------------------------------------------
__device__ unsigned ready_f[32 * 32];   // per-chunk feature-ready flag
__device__ unsigned done_rg[32 * 32];   // per-row-group tile-completion count
__device__ unsigned final_done;        // P2 completion count
__device__ float    partial_rg[32 * 32]; // per-row-group partial sums (padded)

#define GLOAD16(src, dst)                                                     \
  __builtin_amdgcn_global_load_lds(                                           \
      (const __attribute__((address_space(1))) void*)(src),                   \
      (__attribute__((address_space(3))) void*)(dst), 16, 0, 0)

// ---------------------------------------------------------------------------
// One dispatch does everything:
//   P0 (blocks 0..31): bf16 features for 128-row chunk + a[] -> ready flag
//   P1 (all 528):      wait 2 flags -> triangular 128x128 MFMA tile +
//                      fused two-sided LSE partials -> done_rg increments
//   P2 (32 winners):   per-row-group LSE combine -> partial_rg[g]
//   P3 (1 winner):     fixed-order final sum -> out, reset counters
// ---------------------------------------------------------------------------
__global__ __launch_bounds__(256, 4) void fused_all(
    const float* __restrict__ mu_x, const float* __restrict__ sigma_x,
    const float* __restrict__ mu_p, const float* __restrict__ sigma_p,
    __hip_bfloat16* __restrict__ Lf, __hip_bfloat16* __restrict__ Rf,
    float* __restrict__ a, float* __restrict__ lsep, float* __restrict__ pos,
    float* __restrict__ out, float to_add) {
  __shared__ char lt[128 * BK * 2];   // 16 KB
  __shared__ char rt[128 * BK * 2];   // 16 KB
  __shared__ float2 red[128][2];      // 2 KB (reused as reduce scratch)
  __shared__ int p2g[2];

  const int tid = threadIdx.x;
  const int bid = blockIdx.x;

  // decode triangular block index: bid -> (rb, cb), rb <= cb
  int t = bid, rb = 0;
  while (t >= 32 - rb) { t -= 32 - rb; ++rb; }
  const int cb = rb + t;

  // =========== P0: feature producers (blocks 0..31, chunk = bid) ===========
  if (bid < 32) {
    const int wv = tid >> 6;        // wave 0..3 -> row within group of 4
    const int ln = tid & 63;
    const int d0 = ln * 2;          // two d's per lane
    for (int rr = 0; rr < 128; rr += 4) {
      const int row = bid * 128 + rr + wv;
      const float* mup = (row < B_HALF) ? mu_x : mu_p;
      const float* sgp = (row < B_HALF) ? sigma_x : sigma_p;
      const int gi = row & (B_HALF - 1);
      const float2 m2 = *(const float2*)(mup + gi * D_DIM + d0);
      const float2 s2 = *(const float2*)(sgp + gi * D_DIM + d0);
      float var0 = s2.x * s2.x, inv0 = 1.0f / var0, vm0 = var0 + m2.x * m2.x;
      float var1 = s2.y * s2.y, inv1 = 1.0f / var1, vm1 = var1 + m2.y * m2.y;
      size_t base = (size_t)row * K_DIM;
      __hip_bfloat162 h;
#define PK2(P, OFF, X, Y)                                                     \
      h.x = __float2bfloat16(X); h.y = __float2bfloat16(Y);                   \
      *(__hip_bfloat162*)((P) + base + (OFF) + d0) = h;
      PK2(Lf, 0,   inv0, inv1)
      PK2(Lf, 128, vm0, vm1)
      PK2(Lf, 256, m2.x * inv0, m2.y * inv1)
      PK2(Lf, 384, m2.x, m2.y)
      PK2(Rf, 0,   vm0, vm1)
      PK2(Rf, 128, inv0, inv1)
      PK2(Rf, 256, -2.0f * m2.x, -2.0f * m2.y)
      PK2(Rf, 384, -2.0f * m2.x * inv0, -2.0f * m2.y * inv1)
#undef PK2
      float av = m2.x * m2.x * inv0 + m2.y * m2.y * inv1;
#pragma unroll
      for (int x = 1; x < 64; x <<= 1) av += __shfl_xor(av, x);
      if (ln == 0) a[row] = av;
    }
    __syncthreads();   // all stores of this block complete (vmcnt drained)
    if (tid == 0)
      __hip_atomic_store(&ready_f[bid * 32], 1u, __ATOMIC_RELEASE,
                         __HIP_MEMORY_SCOPE_AGENT);
  }

  // =========== wait for the two chunks this tile needs ===========
  if (tid == 0) {
    while (__hip_atomic_load(&ready_f[rb * 32], __ATOMIC_ACQUIRE,
                             __HIP_MEMORY_SCOPE_AGENT) == 0u)
      __builtin_amdgcn_s_sleep(1);
    while (__hip_atomic_load(&ready_f[cb * 32], __ATOMIC_ACQUIRE,
                             __HIP_MEMORY_SCOPE_AGENT) == 0u)
      __builtin_amdgcn_s_sleep(1);
  }
  __syncthreads();

  // =========== P1: triangular tile GEMM + fused epilogue ===========
  {
    const int lane = tid & 63;
    const int wave = tid >> 6;
    const int rowBase = rb * 128, colBase = cb * 128;
    const int wr = wave >> 1, wc = wave & 1;
    const int lx = lane & 15;
    const int rq = lane >> 4;

    f32x4 acc[4][4];
#pragma unroll
    for (int m = 0; m < 4; ++m)
#pragma unroll
      for (int n = 0; n < 4; ++n) acc[m][n] = (f32x4){0.f, 0.f, 0.f, 0.f};

    const int ric   = lane >> 3;
    const int cbyte = ((lane & 7) * 16) ^ (ric << 4);
    const int swzk  = (lane & 7) << 4;

    for (int kk = 0; kk < K_DIM / BK; ++kk) {
      const char* lsrc = (const char*)Lf + (size_t)rowBase * (K_DIM * 2) + kk * (BK * 2);
      const char* rsrc = (const char*)Rf + (size_t)colBase * (K_DIM * 2) + kk * (BK * 2);
#pragma unroll
      for (int t4 = 0; t4 < 4; ++t4) {
        int chunk = wave * 4 + t4;
        GLOAD16(lsrc + (size_t)(chunk * 8 + ric) * (K_DIM * 2) + cbyte, lt + chunk * 1024);
        GLOAD16(rsrc + (size_t)(chunk * 8 + ric) * (K_DIM * 2) + cbyte, rt + chunk * 1024);
      }
      __syncthreads();
#pragma unroll
      for (int ks = 0; ks < 2; ++ks) {
        bf16x8 af[4], bg[4];
        const int kb = ks * 64 + rq * 16;
#pragma unroll
        for (int m = 0; m < 4; ++m) {
          int row = wr * 64 + m * 16 + lx;
          af[m] = *(const bf16x8*)(lt + row * 128 + (kb ^ swzk));
        }
#pragma unroll
        for (int n = 0; n < 4; ++n) {
          int row = wc * 64 + n * 16 + lx;
          bg[n] = *(const bf16x8*)(rt + row * 128 + (kb ^ swzk));
        }
#pragma unroll
        for (int m = 0; m < 4; ++m)
#pragma unroll
          for (int n = 0; n < 4; ++n)
            acc[m][n] = __builtin_amdgcn_mfma_f32_16x16x32_bf16(af[m], bg[n], acc[m][n], 0, 0, 0);
      }
      __syncthreads();
    }

    const float c0 = 640.0f;   // (D/2)/T
    const float c1 = 2.5f;     // 0.25/T
    float aR[4][4];
#pragma unroll
    for (int m = 0; m < 4; ++m)
#pragma unroll
      for (int v = 0; v < 4; ++v)
        aR[m][v] = a[rowBase + wr * 64 + m * 16 + rq * 4 + v];
    float aC[4];
#pragma unroll
    for (int n = 0; n < 4; ++n) aC[n] = a[colBase + wc * 64 + n * 16 + lx];

    // pass 1: acc -> S (diag -> -inf; positive logit += to_add, pos[] writes)
#pragma unroll
    for (int m = 0; m < 4; ++m)
#pragma unroll
      for (int n = 0; n < 4; ++n)
#pragma unroll
        for (int v = 0; v < 4; ++v) {
          int grow = rowBase + wr * 64 + m * 16 + rq * 4 + v;
          int gcol = colBase + wc * 64 + n * 16 + lx;
          float S = c0 - c1 * (acc[m][n][v] + aR[m][v] + aC[n]);
          if (gcol == grow) {
            S = -INFINITY;
          } else if (gcol == (grow ^ B_HALF)) {
            S += to_add;
            pos[grow] = S;   // S symmetric: also row gcol's positive
            pos[gcol] = S;
          }
          acc[m][n][v] = S;
        }

    // pass 2: row partials -> lsep[row][cb]
#pragma unroll
    for (int m = 0; m < 4; ++m)
#pragma unroll
      for (int v = 0; v < 4; ++v) {
        float pm = -INFINITY;
#pragma unroll
        for (int n = 0; n < 4; ++n) pm = fmaxf(pm, acc[m][n][v]);
#pragma unroll
        for (int x = 1; x < 16; x <<= 1) pm = fmaxf(pm, __shfl_xor(pm, x));
        float ps = 0.f;
#pragma unroll
        for (int n = 0; n < 4; ++n) ps += __expf(acc[m][n][v] - pm);
#pragma unroll
        for (int x = 1; x < 16; x <<= 1) ps += __shfl_xor(ps, x);
        if (lx == 0) red[wr * 64 + m * 16 + rq * 4 + v][wc] = make_float2(pm, ps);
      }
    __syncthreads();
    if (tid < 128) {
      float2 p0 = red[tid][0], p1 = red[tid][1];
      float M = fmaxf(p0.x, p1.x);
      float S = p0.y * __expf(p0.x - M) + p1.y * __expf(p1.x - M);
      lsep[(size_t)(rowBase + tid) * NGRP + cb] = M + logf(S);
    }

    // pass 3: column partials -> lsep[col][rb]  (off-diagonal tiles only)
    if (rb != cb) {
      __syncthreads();
#pragma unroll
      for (int n = 0; n < 4; ++n) {
        float cm = -INFINITY;
#pragma unroll
        for (int m = 0; m < 4; ++m)
#pragma unroll
          for (int v = 0; v < 4; ++v) cm = fmaxf(cm, acc[m][n][v]);
        cm = fmaxf(cm, __shfl_xor(cm, 16));
        cm = fmaxf(cm, __shfl_xor(cm, 32));
        float cs = 0.f;
#pragma unroll
        for (int m = 0; m < 4; ++m)
#pragma unroll
          for (int v = 0; v < 4; ++v) cs += __expf(acc[m][n][v] - cm);
        cs += __shfl_xor(cs, 16);
        cs += __shfl_xor(cs, 32);
        if (lane < 16) red[wc * 64 + n * 16 + lane][wr] = make_float2(cm, cs);
      }
      __syncthreads();
      if (tid < 128) {
        float2 p0 = red[tid][0], p1 = red[tid][1];
        float M = fmaxf(p0.x, p1.x);
        float S = p0.y * __expf(p0.x - M) + p1.y * __expf(p1.x - M);
        lsep[(size_t)(colBase + tid) * NGRP + rb] = M + logf(S);
      }
    }
  }

  __syncthreads();   // all lsep/pos stores of this block complete

  // =========== completion counters; winners run P2 / P3 inline ===========
  if (tid == 0) {
    p2g[0] = -1; p2g[1] = -1;
    unsigned v = __hip_atomic_fetch_add(&done_rg[rb * 32], 1u, __ATOMIC_ACQ_REL,
                                        __HIP_MEMORY_SCOPE_AGENT);
    if (v == 31u) p2g[0] = rb;
    if (rb != cb) {
      v = __hip_atomic_fetch_add(&done_rg[cb * 32], 1u, __ATOMIC_ACQ_REL,
                                 __HIP_MEMORY_SCOPE_AGENT);
      if (v == 31u) p2g[1] = cb;
    }
  }
  __syncthreads();

  float* fr = (float*)red;   // 256-float reduce scratch
#pragma unroll
  for (int s = 0; s < 2; ++s) {
    const int g = p2g[s];
    if (g < 0) continue;

    // P2: LSE-combine 128 rows of group g (deterministic per-row order)
    float contrib = 0.f;
    if (tid < 128) {
      const int row = g * 128 + tid;
      const float* lp = lsep + (size_t)row * NGRP;
      float M = lp[0];
#pragma unroll
      for (int k = 1; k < NGRP; ++k) M = fmaxf(M, lp[k]);
      float ssum = 0.f;
#pragma unroll
      for (int k = 0; k < NGRP; ++k) ssum += __expf(lp[k] - M);
      contrib = (M + logf(ssum)) - pos[row];
    }
    fr[tid] = contrib;
    __syncthreads();
#pragma unroll
    for (int off = 128; off > 0; off >>= 1) {
      if (tid < off) fr[tid] += fr[tid + off];
      __syncthreads();
    }
    if (tid == 0) {
      partial_rg[g * 32] = fr[0];
      unsigned v = __hip_atomic_fetch_add(&final_done, 1u, __ATOMIC_ACQ_REL,
                                          __HIP_MEMORY_SCOPE_AGENT);
      if (v == 31u) {
        // P3: final sum, fixed order -> deterministic
        float tot = 0.f;
        for (int k = 0; k < 32; ++k) tot += partial_rg[k * 32];
        out[0] = tot * (1.0f / 4096.0f);
        // reset all counters for the next graph replay (all increments
        // happen-before this point via the acquire chain)
        for (int k = 0; k < 32; ++k) {
          __hip_atomic_store(&ready_f[k * 32], 0u, __ATOMIC_RELAXED,
                             __HIP_MEMORY_SCOPE_AGENT);
          __hip_atomic_store(&done_rg[k * 32], 0u, __ATOMIC_RELAXED,
                             __HIP_MEMORY_SCOPE_AGENT);
        }
        __hip_atomic_store(&final_done, 0u, __ATOMIC_RELAXED,
                           __HIP_MEMORY_SCOPE_AGENT);
      }
    }
    __syncthreads();
  }
}

// ===========================================================================
extern "C" void kernel_launch(void* const* d_in, const int* in_sizes, int n_in,
                              void* d_out, int out_size, void* d_ws, size_t ws_size,
                              hipStream_t stream) {
  const float* mu_x    = (const float*)d_in[1];
  const float* sigma_x = (const float*)d_in[2];
  const float* mu_p    = (const float*)d_in[3];
  const float* sigma_p = (const float*)d_in[4];
  float* out = (float*)d_out;

  float to_add = (float)(-log((4095.0 - 1.0 / 5.0) / 4094.0));

  const size_t featB = (size_t)N_TOT * K_DIM * 2;   // 4 MB each
  char* ws = (char*)d_ws;
  __hip_bfloat16* Lf = (__hip_bfloat16*)(ws);
  __hip_bfloat16* Rf = (__hip_bfloat16*)(ws + featB);
  float* a    = (float*)(ws + 2 * featB);                    // 16 KB
  float* lsep = (float*)(ws + 2 * featB + 16384);            // 512 KB
  float* pos  = (float*)(ws + 2 * featB + 16384 + 524288);   // 16 KB

  fused_all<<<dim3(NBLK), dim3(256), 0, stream>>>(
      mu_x, sigma_x, mu_p, sigma_p, Lf, Rf, a, lsep, pos, out, to_add);
}

// Round 6
// 50.901 us; speedup vs baseline: 3.8393x; 3.8393x over previous
//
#include <hip/hip_runtime.h>
#include <hip/hip_bf16.h>
#include <math.h>

typedef short bf16x8 __attribute__((ext_vector_type(8)));
typedef float f32x4 __attribute__((ext_vector_type(4)));

#define B_HALF 2048
#define N_TOT  4096
#define D_DIM  128
#define K_DIM  512
#define BK     64
#define NGRP   32
#define NBLK   528   // triangular 32x32 tile grid (528 % 8 == 0)

// winner counter for the merged final reduction (zero at load; winner resets
// -> deterministic across graph replays; increment-only, nobody spins)
__device__ unsigned red_done;

// ---------------------------------------------------------------------------
// P0: bf16 features + a[].  256 blocks x 256 thr, 16 rows/block.
// L_i = [inv, var+mu2, mu*inv, mu]; R_j = [var+mu2, inv, -2mu, -2mu*inv]
// a_i = sum_d mu^2 * inv   (L_i . R_j symmetric)
// ---------------------------------------------------------------------------
__global__ __launch_bounds__(256) void prep_feat(
    const float* __restrict__ mu_x, const float* __restrict__ sigma_x,
    const float* __restrict__ mu_p, const float* __restrict__ sigma_p,
    __hip_bfloat16* __restrict__ Lf, __hip_bfloat16* __restrict__ Rf,
    float* __restrict__ a) {
  const int tid = threadIdx.x;
  const int wv = tid >> 6;        // wave -> row within group of 4
  const int ln = tid & 63;
  const int d0 = ln * 2;          // two d's per lane
#pragma unroll
  for (int rr = 0; rr < 16; rr += 4) {
    const int row = blockIdx.x * 16 + rr + wv;
    const float* mup = (row < B_HALF) ? mu_x : mu_p;
    const float* sgp = (row < B_HALF) ? sigma_x : sigma_p;
    const int gi = row & (B_HALF - 1);
    const float2 m2 = *(const float2*)(mup + gi * D_DIM + d0);
    const float2 s2 = *(const float2*)(sgp + gi * D_DIM + d0);
    float var0 = s2.x * s2.x, inv0 = 1.0f / var0, vm0 = var0 + m2.x * m2.x;
    float var1 = s2.y * s2.y, inv1 = 1.0f / var1, vm1 = var1 + m2.y * m2.y;
    size_t base = (size_t)row * K_DIM;
    __hip_bfloat162 h;
#define PK2(P, OFF, X, Y)                                                     \
    h.x = __float2bfloat16(X); h.y = __float2bfloat16(Y);                     \
    *(__hip_bfloat162*)((P) + base + (OFF) + d0) = h;
    PK2(Lf, 0,   inv0, inv1)
    PK2(Lf, 128, vm0, vm1)
    PK2(Lf, 256, m2.x * inv0, m2.y * inv1)
    PK2(Lf, 384, m2.x, m2.y)
    PK2(Rf, 0,   vm0, vm1)
    PK2(Rf, 128, inv0, inv1)
    PK2(Rf, 256, -2.0f * m2.x, -2.0f * m2.y)
    PK2(Rf, 384, -2.0f * m2.x * inv0, -2.0f * m2.y * inv1)
#undef PK2
    float av = m2.x * m2.x * inv0 + m2.y * m2.y * inv1;
#pragma unroll
    for (int x = 1; x < 64; x <<= 1) av += __shfl_xor(av, x);
    if (ln == 0) a[row] = av;
  }
}

#define GLOAD16(src, dst)                                                     \
  __builtin_amdgcn_global_load_lds(                                           \
      (const __attribute__((address_space(1))) void*)(src),                   \
      (__attribute__((address_space(3))) void*)(dst), 16, 0, 0)

// ---------------------------------------------------------------------------
// P1: triangular 128x128 MFMA tile + fused two-sided LSE partials.
// Double-buffered LDS: issue next K-chunk's global_load_lds BEFORE computing
// the current one; the single __syncthreads per step (vmcnt(0)+barrier)
// lands after ~32 MFMAs so the L2 latency is hidden.
// LDS linear dest + pre-swizzled global source, read-side XOR (rule #21).
// ---------------------------------------------------------------------------
__global__ __launch_bounds__(256, 2) void gemm_lse(
    const __hip_bfloat16* __restrict__ Lf, const __hip_bfloat16* __restrict__ Rf,
    const float* __restrict__ a,
    float* __restrict__ lsep, float* __restrict__ pos, float to_add) {
  __shared__ char lt[2][128 * BK * 2];   // 2 x 16 KB
  __shared__ char rt[2][128 * BK * 2];   // 2 x 16 KB
  __shared__ float2 red[128][2];         // 2 KB

  // XCD-chunked bijective swizzle: hw XCD = bid%8 gets contiguous tile range
  const int sb = (blockIdx.x & 7) * (NBLK / 8) + (blockIdx.x >> 3);
  int t = sb, rb = 0;
  while (t >= 32 - rb) { t -= 32 - rb; ++rb; }
  const int cb = rb + t;

  const int tid  = threadIdx.x;
  const int lane = tid & 63;
  const int wave = tid >> 6;
  const int rowBase = rb * 128, colBase = cb * 128;
  const int wr = wave >> 1, wc = wave & 1;
  const int lx = lane & 15;
  const int rq = lane >> 4;

  f32x4 acc[4][4];
#pragma unroll
  for (int m = 0; m < 4; ++m)
#pragma unroll
    for (int n = 0; n < 4; ++n) acc[m][n] = (f32x4){0.f, 0.f, 0.f, 0.f};

  const int ric   = lane >> 3;
  const int cbyte = ((lane & 7) * 16) ^ (ric << 4);
  const int swzk  = (lane & 7) << 4;
  const char* lsrc0 = (const char*)Lf + (size_t)rowBase * (K_DIM * 2);
  const char* rsrc0 = (const char*)Rf + (size_t)colBase * (K_DIM * 2);

#define STAGE(KK, NB)                                                         \
  {                                                                           \
    const char* ls = lsrc0 + (KK) * (BK * 2);                                 \
    const char* rs = rsrc0 + (KK) * (BK * 2);                                 \
    _Pragma("unroll")                                                         \
    for (int t4 = 0; t4 < 4; ++t4) {                                          \
      int chunk = wave * 4 + t4;                                              \
      GLOAD16(ls + (size_t)(chunk * 8 + ric) * (K_DIM * 2) + cbyte,           \
              &lt[NB][chunk * 1024]);                                         \
      GLOAD16(rs + (size_t)(chunk * 8 + ric) * (K_DIM * 2) + cbyte,           \
              &rt[NB][chunk * 1024]);                                         \
    }                                                                         \
  }

  STAGE(0, 0)
  __syncthreads();

  for (int kk = 0; kk < K_DIM / BK; ++kk) {
    const int cur = kk & 1;
    if (kk < K_DIM / BK - 1) STAGE(kk + 1, cur ^ 1)   // prefetch next chunk
#pragma unroll
    for (int ks = 0; ks < 2; ++ks) {
      bf16x8 af[4], bg[4];
      const int kb = ks * 64 + rq * 16;
#pragma unroll
      for (int m = 0; m < 4; ++m) {
        int row = wr * 64 + m * 16 + lx;
        af[m] = *(const bf16x8*)(&lt[cur][row * 128 + (kb ^ swzk)]);
      }
#pragma unroll
      for (int n = 0; n < 4; ++n) {
        int row = wc * 64 + n * 16 + lx;
        bg[n] = *(const bf16x8*)(&rt[cur][row * 128 + (kb ^ swzk)]);
      }
#pragma unroll
      for (int m = 0; m < 4; ++m)
#pragma unroll
        for (int n = 0; n < 4; ++n)
          acc[m][n] = __builtin_amdgcn_mfma_f32_16x16x32_bf16(af[m], bg[n], acc[m][n], 0, 0, 0);
    }
    __syncthreads();   // drains vmcnt (prefetch landed during MFMA) + barrier
  }
#undef STAGE

  // ---- fused epilogue (proven in R3) ----
  const float c0 = 640.0f;   // (D/2)/T
  const float c1 = 2.5f;     // 0.25/T
  float aR[4][4];
#pragma unroll
  for (int m = 0; m < 4; ++m)
#pragma unroll
    for (int v = 0; v < 4; ++v)
      aR[m][v] = a[rowBase + wr * 64 + m * 16 + rq * 4 + v];
  float aC[4];
#pragma unroll
  for (int n = 0; n < 4; ++n) aC[n] = a[colBase + wc * 64 + n * 16 + lx];

  // pass 1: acc -> S (diag -> -inf; positive logit += to_add, pos[] writes)
#pragma unroll
  for (int m = 0; m < 4; ++m)
#pragma unroll
    for (int n = 0; n < 4; ++n)
#pragma unroll
      for (int v = 0; v < 4; ++v) {
        int grow = rowBase + wr * 64 + m * 16 + rq * 4 + v;
        int gcol = colBase + wc * 64 + n * 16 + lx;
        float S = c0 - c1 * (acc[m][n][v] + aR[m][v] + aC[n]);
        if (gcol == grow) {
          S = -INFINITY;
        } else if (gcol == (grow ^ B_HALF)) {
          S += to_add;
          pos[grow] = S;   // S symmetric: also row gcol's positive
          pos[gcol] = S;
        }
        acc[m][n][v] = S;
      }

  // pass 2: row partials -> lsep[row][cb]
#pragma unroll
  for (int m = 0; m < 4; ++m)
#pragma unroll
    for (int v = 0; v < 4; ++v) {
      float pm = -INFINITY;
#pragma unroll
      for (int n = 0; n < 4; ++n) pm = fmaxf(pm, acc[m][n][v]);
#pragma unroll
      for (int x = 1; x < 16; x <<= 1) pm = fmaxf(pm, __shfl_xor(pm, x));
      float ps = 0.f;
#pragma unroll
      for (int n = 0; n < 4; ++n) ps += __expf(acc[m][n][v] - pm);
#pragma unroll
      for (int x = 1; x < 16; x <<= 1) ps += __shfl_xor(ps, x);
      if (lx == 0) red[wr * 64 + m * 16 + rq * 4 + v][wc] = make_float2(pm, ps);
    }
  __syncthreads();
  if (tid < 128) {
    float2 p0 = red[tid][0], p1 = red[tid][1];
    float M = fmaxf(p0.x, p1.x);
    float S = p0.y * __expf(p0.x - M) + p1.y * __expf(p1.x - M);
    lsep[(size_t)(rowBase + tid) * NGRP + cb] = M + logf(S);
  }

  // pass 3: column partials -> lsep[col][rb]  (off-diagonal tiles only)
  if (rb != cb) {
    __syncthreads();
#pragma unroll
    for (int n = 0; n < 4; ++n) {
      float cm = -INFINITY;
#pragma unroll
      for (int m = 0; m < 4; ++m)
#pragma unroll
        for (int v = 0; v < 4; ++v) cm = fmaxf(cm, acc[m][n][v]);
      cm = fmaxf(cm, __shfl_xor(cm, 16));
      cm = fmaxf(cm, __shfl_xor(cm, 32));
      float cs = 0.f;
#pragma unroll
      for (int m = 0; m < 4; ++m)
#pragma unroll
        for (int v = 0; v < 4; ++v) cs += __expf(acc[m][n][v] - cm);
      cs += __shfl_xor(cs, 16);
      cs += __shfl_xor(cs, 32);
      if (lane < 16) red[wc * 64 + n * 16 + lane][wr] = make_float2(cm, cs);
    }
    __syncthreads();
    if (tid < 128) {
      float2 p0 = red[tid][0], p1 = red[tid][1];
      float M = fmaxf(p0.x, p1.x);
      float S = p0.y * __expf(p0.x - M) + p1.y * __expf(p1.x - M);
      lsep[(size_t)(colBase + tid) * NGRP + rb] = M + logf(S);
    }
  }
}

// ---------------------------------------------------------------------------
// P2+P3 merged: 16 blocks x 256 thr, 1 row/thread. Block partials -> ws;
// last finisher (fetch_add returns 15) sums the 16 partials in fixed index
// order (deterministic) and resets the counter.
// ---------------------------------------------------------------------------
__global__ __launch_bounds__(256) void reduce_final(
    const float* __restrict__ lsep, const float* __restrict__ pos,
    float* __restrict__ partial, float* __restrict__ out) {
  const int tid = threadIdx.x;
  const int row = blockIdx.x * 256 + tid;
  const float* lp = lsep + (size_t)row * NGRP;
  float M = lp[0];
#pragma unroll
  for (int k = 1; k < NGRP; ++k) M = fmaxf(M, lp[k]);
  float s = 0.f;
#pragma unroll
  for (int k = 0; k < NGRP; ++k) s += __expf(lp[k] - M);
  float contrib = (M + logf(s)) - pos[row];

  __shared__ float fr[256];
  fr[tid] = contrib;
  __syncthreads();
#pragma unroll
  for (int off = 128; off > 0; off >>= 1) {
    if (tid < off) fr[tid] += fr[tid + off];
    __syncthreads();
  }
  if (tid == 0) {
    partial[blockIdx.x] = fr[0];
    unsigned v = __hip_atomic_fetch_add(&red_done, 1u, __ATOMIC_ACQ_REL,
                                        __HIP_MEMORY_SCOPE_AGENT);
    if (v == 15u) {
      float tot = 0.f;
      for (int k = 0; k < 16; ++k) tot += partial[k];
      out[0] = tot * (1.0f / 4096.0f);
      __hip_atomic_store(&red_done, 0u, __ATOMIC_RELAXED,
                         __HIP_MEMORY_SCOPE_AGENT);
    }
  }
}

// ===========================================================================
extern "C" void kernel_launch(void* const* d_in, const int* in_sizes, int n_in,
                              void* d_out, int out_size, void* d_ws, size_t ws_size,
                              hipStream_t stream) {
  const float* mu_x    = (const float*)d_in[1];
  const float* sigma_x = (const float*)d_in[2];
  const float* mu_p    = (const float*)d_in[3];
  const float* sigma_p = (const float*)d_in[4];
  float* out = (float*)d_out;

  float to_add = (float)(-log((4095.0 - 1.0 / 5.0) / 4094.0));

  const size_t featB = (size_t)N_TOT * K_DIM * 2;   // 4 MB each
  char* ws = (char*)d_ws;
  __hip_bfloat16* Lf = (__hip_bfloat16*)(ws);
  __hip_bfloat16* Rf = (__hip_bfloat16*)(ws + featB);
  float* a       = (float*)(ws + 2 * featB);                    // 16 KB
  float* lsep    = (float*)(ws + 2 * featB + 16384);            // 512 KB
  float* pos     = (float*)(ws + 2 * featB + 16384 + 524288);   // 16 KB
  float* partial = (float*)(ws + 2 * featB + 16384 + 524288 + 16384);

  prep_feat<<<dim3(256), dim3(256), 0, stream>>>(mu_x, sigma_x, mu_p, sigma_p,
                                                 Lf, Rf, a);
  gemm_lse<<<dim3(NBLK), dim3(256), 0, stream>>>(Lf, Rf, a, lsep, pos, to_add);
  reduce_final<<<dim3(16), dim3(256), 0, stream>>>(lsep, pos, partial, out);
}